// Round 16
// baseline (252.835 us; speedup 1.0000x reference)
//
#include <hip/hip_runtime.h>

#define HID 128
#define CAP 8960   // per-bucket edge capacity (avg 8192, +8.5 sigma)
#define EPB 4096   // edges per bucket block

typedef __attribute__((ext_vector_type(8))) short bf16x8;
typedef __attribute__((ext_vector_type(4))) float f32x4;
typedef __attribute__((ext_vector_type(2))) float f32x2;

__device__ __forceinline__ unsigned short f2bf(float f) {
  unsigned u = __builtin_bit_cast(unsigned, f);
  u += 0x7FFFu + ((u >> 16) & 1u);  // RNE
  return (unsigned short)(u >> 16);
}
__device__ __forceinline__ float bflo(unsigned v) {
  return __builtin_bit_cast(float, v << 16);
}
__device__ __forceinline__ float bfhi(unsigned v) {
  return __builtin_bit_cast(float, v & 0xFFFF0000u);
}
__device__ __forceinline__ unsigned pck(float a, float b) {
  return (unsigned)f2bf(a) | ((unsigned)f2bf(b) << 16);
}

// ---------------- launch 2: bucket sort | prep weights | lin1 (role split) ----------------

__global__ __launch_bounds__(256) void k_pre(
    const float* __restrict__ x, const float* __restrict__ w1, const float* __restrict__ b1,
    const float* __restrict__ wc1, const float* __restrict__ wc2,
    const float* __restrict__ w5b, const float* __restrict__ w2,
    unsigned short* __restrict__ wc1t, unsigned short* __restrict__ wc2t,
    unsigned short* __restrict__ w5bt, unsigned short* __restrict__ w2t,
    unsigned* __restrict__ x1,
    const int* __restrict__ erow, const int* __restrict__ ecol,
    int* __restrict__ gcnt, unsigned* __restrict__ ebuf, int e, int bgrid, int n) {
  __shared__ int hist[256], base[256], cur[256];
  int b = blockIdx.x;
  int tid = threadIdx.x;
  if (b < bgrid) {
    // bucket sort by c>>8 (gcnt pre-zeroed via memset); packed r | lc<<16
    hist[tid] = 0;
    cur[tid] = 0;
    __syncthreads();
    int eb = b * EPB;
    int cc[16], rr[16];
#pragma unroll
    for (int k = 0; k < 16; ++k) {
      int i = eb + k * 256 + tid;
      if (i < e) {
        cc[k] = ecol[i];
        rr[k] = erow[i];
        atomicAdd(&hist[cc[k] >> 8], 1);
      } else {
        cc[k] = -1;
        rr[k] = 0;
      }
    }
    __syncthreads();
    if (hist[tid]) base[tid] = atomicAdd(&gcnt[tid], hist[tid]);
    __syncthreads();
#pragma unroll
    for (int k = 0; k < 16; ++k) {
      if (cc[k] >= 0) {
        int bk = cc[k] >> 8;
        int slot = base[bk] + atomicAdd(&cur[bk], 1);
        if (slot < CAP)
          ebuf[(size_t)bk * CAP + slot] = (unsigned)rr[k] | ((unsigned)(cc[k] & 255) << 16);
      }
    }
    return;
  }
  b -= bgrid;
  if (b < 384) {
    int idx = b * 256 + tid;
    if (idx < 16384) {
      int nn = idx >> 7, k = idx & 127;
      wc1t[idx] = f2bf(wc1[k * HID + nn]);
    } else if (idx < 32768) {
      int e2 = idx - 16384, nn = e2 >> 7, k = e2 & 127;
      wc2t[e2] = f2bf(wc2[k * HID + nn]);
    } else if (idx < 49152) {
      int e2 = idx - 32768, nn = e2 >> 7, k = e2 & 127;
      w5bt[e2] = f2bf(w5b[k * HID + nn]);
    } else if (idx < 98304) {
      int e2 = idx - 49152, nn = e2 / 384, k = e2 - nn * 384;
      w2t[e2] = f2bf(w2[k * HID + nn]);
    }
    return;
  }
  b -= 384;
  int idx = b * 256 + tid;
  if (idx >= n * 64) return;
  int i = idx >> 6, j = (idx & 63) * 2;
  float x0 = x[i * 3], xv1 = x[i * 3 + 1], xv2 = x[i * 3 + 2];
  float v0 = b1[j] + x0 * w1[j] + xv1 * w1[HID + j] + xv2 * w1[2 * HID + j];
  float v1 = b1[j + 1] + x0 * w1[j + 1] + xv1 * w1[HID + j + 1] + xv2 * w1[2 * HID + j + 1];
  x1[idx] = pck(v0, v1);
}

// ---------------- conv GEMM body: 32 rows x 128 cols per block (4 waves 2x2) ----------------
// bf16 in/weights, fp8 e4m3 out.

__device__ __forceinline__ void gconv_body(int bid, const unsigned short* __restrict__ A,
                                           const unsigned short* __restrict__ Bt,
                                           unsigned char* __restrict__ C, int n) {
  int tid = threadIdx.x, lane = tid & 63, wave = tid >> 6;
  int lm = lane & 15, lk = lane >> 4;
  int row0 = bid * 32 + (wave >> 1) * 16;
  int col0 = (wave & 1) * 64;
  int ra = min(row0 + lm, n - 1);
  f32x4 acc[4] = {};
#pragma unroll
  for (int ks = 0; ks < 4; ++ks) {
    bf16x8 a0 = *reinterpret_cast<const bf16x8*>(A + (size_t)ra * HID + ks * 32 + lk * 8);
#pragma unroll
    for (int ct = 0; ct < 4; ++ct) {
      bf16x8 bb = *reinterpret_cast<const bf16x8*>(Bt + (size_t)(col0 + ct * 16 + lm) * HID + ks * 32 + lk * 8);
      acc[ct] = __builtin_amdgcn_mfma_f32_16x16x32_bf16(a0, bb, acc[ct], 0, 0, 0);
    }
  }
#pragma unroll
  for (int r = 0; r < 4; ++r) {
    int row = row0 + lk * 4 + r;
    if (row < n) {
      int pa = __builtin_amdgcn_cvt_pk_fp8_f32(acc[0][r], acc[1][r], 0, false);
      int pb = __builtin_amdgcn_cvt_pk_fp8_f32(acc[2][r], acc[3][r], 0, false);
      size_t base = (size_t)row * HID + col0 + lm;
      C[base]      = (unsigned char)(pa & 0xFF);
      C[base + 16] = (unsigned char)((pa >> 8) & 0xFF);
      C[base + 32] = (unsigned char)(pb & 0xFF);
      C[base + 48] = (unsigned char)((pb >> 8) & 0xFF);
    }
  }
}

// ---------------- launch 3: per-bucket CSR build || conv1 GEMM (role split) ----------------

__global__ __launch_bounds__(256) void k_csrconv(
    const unsigned* __restrict__ ebuf, const int* __restrict__ gcnt,
    int* __restrict__ csr, int* __restrict__ offg, int* __restrict__ cnt,
    float* __restrict__ dinv,
    const unsigned short* __restrict__ A, const unsigned short* __restrict__ Bt,
    unsigned char* __restrict__ C, int n, int nbkt) {
  __shared__ int hist[256], scan[256], cur[256];
  int tid = threadIdx.x, b = blockIdx.x;
  if (b < nbkt) {
    int m = min(gcnt[b], CAP);
    hist[tid] = 0;
    cur[tid] = 0;
    __syncthreads();
    const unsigned* eb = ebuf + (size_t)b * CAP;
    for (int i = tid; i < m; i += 256) atomicAdd(&hist[(eb[i] >> 16) & 255], 1);
    __syncthreads();
    scan[tid] = hist[tid];
    __syncthreads();
    for (int d = 1; d < 256; d <<= 1) {
      int t = (tid >= d) ? scan[tid - d] : 0;
      __syncthreads();
      scan[tid] += t;
      __syncthreads();
    }
    scan[tid] -= hist[tid];  // exclusive
    int c = b * 256 + tid;
    if (c < n) {
      cnt[c] = hist[tid];
      offg[c] = b * CAP + scan[tid];
      dinv[c] = rsqrtf((float)hist[tid] + 1.0f);
    }
    __syncthreads();
    int* cb = csr + (size_t)b * CAP;
    for (int i = tid; i < m; i += 256) {
      unsigned eg = eb[i];
      int lc = (eg >> 16) & 255;
      cb[scan[lc] + atomicAdd(&cur[lc], 1)] = (int)(eg & 0xFFFF);
    }
    return;
  }
  gconv_body(b - nbkt, A, Bt, C, n);
}

__global__ void k_gconv(const unsigned short* __restrict__ A,
                        const unsigned short* __restrict__ Bt,
                        unsigned char* __restrict__ C, int n) {
  gconv_body(blockIdx.x, A, Bt, C, n);
}

// ---------------- GCN aggregation: wave/node, 8 groups x 8 lanes x 16B(fp8) ----------------
// 16 edges/iter, rotated csr/dinv prefetch (R15-proven).

__global__ __launch_bounds__(256) void k_agg(const uint4* __restrict__ h,
                                             const float* __restrict__ dinv,
                                             const int* __restrict__ offg,
                                             const int* __restrict__ cnt,
                                             const int* __restrict__ csr,
                                             const float* __restrict__ bias,
                                             uint4* __restrict__ out, int n) {
  int wave = threadIdx.x >> 6, lane = threadIdx.x & 63;
  int c = blockIdx.x * 4 + wave;
  if (c >= n) return;
  int g = lane >> 3, cp = lane & 7;
  float dc = dinv[c];
  float acc[16];
  {
    uint4 v = h[(size_t)c * 8 + cp];
    float ws = (g == 0) ? dc : 0.f;  // self-loop term dc*h[c]
    f32x2 p;
    p = __builtin_amdgcn_cvt_pk_f32_fp8((int)v.x, false); acc[0] = p.x * ws; acc[1] = p.y * ws;
    p = __builtin_amdgcn_cvt_pk_f32_fp8((int)v.x, true);  acc[2] = p.x * ws; acc[3] = p.y * ws;
    p = __builtin_amdgcn_cvt_pk_f32_fp8((int)v.y, false); acc[4] = p.x * ws; acc[5] = p.y * ws;
    p = __builtin_amdgcn_cvt_pk_f32_fp8((int)v.y, true);  acc[6] = p.x * ws; acc[7] = p.y * ws;
    p = __builtin_amdgcn_cvt_pk_f32_fp8((int)v.z, false); acc[8] = p.x * ws; acc[9] = p.y * ws;
    p = __builtin_amdgcn_cvt_pk_f32_fp8((int)v.z, true);  acc[10] = p.x * ws; acc[11] = p.y * ws;
    p = __builtin_amdgcn_cvt_pk_f32_fp8((int)v.w, false); acc[12] = p.x * ws; acc[13] = p.y * ws;
    p = __builtin_amdgcn_cvt_pk_f32_fp8((int)v.w, true);  acc[14] = p.x * ws; acc[15] = p.y * ws;
  }
  int s = offg[c], t = s + cnt[c];
  int j0 = s + g, j1 = s + 8 + g;
  bool v0 = j0 < t, v1 = j1 < t;
  int r0 = csr[v0 ? j0 : s];
  int r1 = csr[v1 ? j1 : s];
  float w0 = v0 ? dinv[r0] : 0.f;
  float w1 = v1 ? dinv[r1] : 0.f;
  for (int idx = s; idx < t; idx += 16) {
    uint4 h0 = h[(size_t)r0 * 8 + cp];
    uint4 h1 = h[(size_t)r1 * 8 + cp];
    int jn0 = idx + 16 + g, jn1 = idx + 24 + g;
    bool nv0 = jn0 < t, nv1 = jn1 < t;
    int nr0 = csr[nv0 ? jn0 : s];
    int nr1 = csr[nv1 ? jn1 : s];
    float nw0 = nv0 ? dinv[nr0] : 0.f;
    float nw1 = nv1 ? dinv[nr1] : 0.f;
    f32x2 p;
#define ACC8(vv, ww)                                                                     \
    p = __builtin_amdgcn_cvt_pk_f32_fp8((int)vv.x, false); acc[0] = fmaf(p.x, ww, acc[0]); acc[1] = fmaf(p.y, ww, acc[1]); \
    p = __builtin_amdgcn_cvt_pk_f32_fp8((int)vv.x, true);  acc[2] = fmaf(p.x, ww, acc[2]); acc[3] = fmaf(p.y, ww, acc[3]); \
    p = __builtin_amdgcn_cvt_pk_f32_fp8((int)vv.y, false); acc[4] = fmaf(p.x, ww, acc[4]); acc[5] = fmaf(p.y, ww, acc[5]); \
    p = __builtin_amdgcn_cvt_pk_f32_fp8((int)vv.y, true);  acc[6] = fmaf(p.x, ww, acc[6]); acc[7] = fmaf(p.y, ww, acc[7]); \
    p = __builtin_amdgcn_cvt_pk_f32_fp8((int)vv.z, false); acc[8] = fmaf(p.x, ww, acc[8]); acc[9] = fmaf(p.y, ww, acc[9]); \
    p = __builtin_amdgcn_cvt_pk_f32_fp8((int)vv.z, true);  acc[10] = fmaf(p.x, ww, acc[10]); acc[11] = fmaf(p.y, ww, acc[11]); \
    p = __builtin_amdgcn_cvt_pk_f32_fp8((int)vv.w, false); acc[12] = fmaf(p.x, ww, acc[12]); acc[13] = fmaf(p.y, ww, acc[13]); \
    p = __builtin_amdgcn_cvt_pk_f32_fp8((int)vv.w, true);  acc[14] = fmaf(p.x, ww, acc[14]); acc[15] = fmaf(p.y, ww, acc[15]);
    ACC8(h0, w0)
    ACC8(h1, w1)
#undef ACC8
    r0 = nr0; r1 = nr1; w0 = nw0; w1 = nw1;
  }
#pragma unroll
  for (int i = 0; i < 16; ++i) {
    acc[i] += __shfl_xor(acc[i], 8);
    acc[i] += __shfl_xor(acc[i], 16);
    acc[i] += __shfl_xor(acc[i], 32);
  }
  if (g == 0) {
    int cb = cp * 16;
    uint4 o1, o2;
    o1.x = pck(fmaxf(fmaf(acc[0], dc, bias[cb + 0]), 0.f), fmaxf(fmaf(acc[1], dc, bias[cb + 1]), 0.f));
    o1.y = pck(fmaxf(fmaf(acc[2], dc, bias[cb + 2]), 0.f), fmaxf(fmaf(acc[3], dc, bias[cb + 3]), 0.f));
    o1.z = pck(fmaxf(fmaf(acc[4], dc, bias[cb + 4]), 0.f), fmaxf(fmaf(acc[5], dc, bias[cb + 5]), 0.f));
    o1.w = pck(fmaxf(fmaf(acc[6], dc, bias[cb + 6]), 0.f), fmaxf(fmaf(acc[7], dc, bias[cb + 7]), 0.f));
    o2.x = pck(fmaxf(fmaf(acc[8], dc, bias[cb + 8]), 0.f), fmaxf(fmaf(acc[9], dc, bias[cb + 9]), 0.f));
    o2.y = pck(fmaxf(fmaf(acc[10], dc, bias[cb + 10]), 0.f), fmaxf(fmaf(acc[11], dc, bias[cb + 11]), 0.f));
    o2.z = pck(fmaxf(fmaf(acc[12], dc, bias[cb + 12]), 0.f), fmaxf(fmaf(acc[13], dc, bias[cb + 13]), 0.f));
    o2.w = pck(fmaxf(fmaf(acc[14], dc, bias[cb + 14]), 0.f), fmaxf(fmaf(acc[15], dc, bias[cb + 15]), 0.f));
    out[(size_t)c * 16 + cp * 2] = o1;
    out[(size_t)c * 16 + cp * 2 + 1] = o2;
  }
}

// ---------------- nv GEMM: 32 rows/block, [x1|x2|x3](K=384) @ w2t + b2 ----------------
// writes nv f32 (output), relu(nv) bf16 (for q GEMM), masked col-partials (pool).

__global__ __launch_bounds__(256) void k_gnv(const unsigned short* __restrict__ A1,
                                             const unsigned short* __restrict__ A2,
                                             const unsigned short* __restrict__ A3,
                                             const unsigned short* __restrict__ Bt,
                                             const float* __restrict__ b2,
                                             const int* __restrict__ sel,
                                             float* __restrict__ nv,
                                             unsigned short* __restrict__ nvr,
                                             float* __restrict__ part, int n) {
  __shared__ float spart[HID];
  int tid = threadIdx.x, lane = tid & 63, wave = tid >> 6;
  if (tid < HID) spart[tid] = 0.f;
  int lm = lane & 15, lk = lane >> 4;
  int row0 = blockIdx.x * 32 + (wave >> 1) * 16;
  int col0 = (wave & 1) * 64;
  int ra = min(row0 + lm, n - 1);
  f32x4 acc[4] = {};
  const unsigned short* As[3] = {A1, A2, A3};
#pragma unroll
  for (int kb = 0; kb < 3; ++kb) {
    const unsigned short* A = As[kb];
#pragma unroll
    for (int ks = 0; ks < 4; ++ks) {
      bf16x8 a0 = *reinterpret_cast<const bf16x8*>(A + (size_t)ra * HID + ks * 32 + lk * 8);
#pragma unroll
      for (int ct = 0; ct < 4; ++ct) {
        bf16x8 bb = *reinterpret_cast<const bf16x8*>(
            Bt + (size_t)(col0 + ct * 16 + lm) * 384 + kb * 128 + ks * 32 + lk * 8);
        acc[ct] = __builtin_amdgcn_mfma_f32_16x16x32_bf16(a0, bb, acc[ct], 0, 0, 0);
      }
    }
  }
  float psum[4] = {0.f, 0.f, 0.f, 0.f};
#pragma unroll
  for (int r = 0; r < 4; ++r) {
    int row = row0 + lk * 4 + r;
    if (row < n) {
      float m = (sel[row] == 0) ? 1.f : 0.f;
#pragma unroll
      for (int ct = 0; ct < 4; ++ct) {
        int col = col0 + ct * 16 + lm;
        float v = acc[ct][r] + b2[col];
        nv[(size_t)row * HID + col] = v;
        nvr[(size_t)row * HID + col] = f2bf(fmaxf(v, 0.f));
        psum[ct] = fmaf(m, v, psum[ct]);
      }
    }
  }
#pragma unroll
  for (int ct = 0; ct < 4; ++ct) {
    psum[ct] += __shfl_xor(psum[ct], 16);
    psum[ct] += __shfl_xor(psum[ct], 32);
  }
  __syncthreads();
  if (lk == 0) {
#pragma unroll
    for (int ct = 0; ct < 4; ++ct) atomicAdd(&spart[col0 + ct * 16 + lm], psum[ct]);
  }
  __syncthreads();
  if (tid < HID) part[(size_t)blockIdx.x * HID + tid] = spart[tid];
}

// ---------------- parallel pool-final + g + gb5 (1 block x 1024 thr) ----------------

__global__ __launch_bounds__(1024) void k_g(const float* __restrict__ part, int nblk,
                                            const float* __restrict__ w6, const float* __restrict__ b6,
                                            const float* __restrict__ w5, const float* __restrict__ b5,
                                            float* __restrict__ gb5) {
  __shared__ float red[8][HID];
  __shared__ float p0[HID], gl[HID];
  int t = threadIdx.x, j = t & 127, grp = t >> 7;
  float a0 = 0.f, a1 = 0.f, a2 = 0.f, a3 = 0.f;
  int r = grp;
  for (; r + 32 <= nblk; r += 32) {
    a0 += part[(size_t)(r)*HID + j];
    a1 += part[(size_t)(r + 8) * HID + j];
    a2 += part[(size_t)(r + 16) * HID + j];
    a3 += part[(size_t)(r + 24) * HID + j];
  }
  for (; r < nblk; r += 8) a0 += part[(size_t)r * HID + j];
  red[grp][j] = (a0 + a1) + (a2 + a3);
  __syncthreads();
  if (grp == 0)
    p0[j] = ((red[0][j] + red[1][j]) + (red[2][j] + red[3][j])) +
            ((red[4][j] + red[5][j]) + (red[6][j] + red[7][j]));
  __syncthreads();
  float acc = 0.f;
#pragma unroll
  for (int k = 0; k < 16; ++k) acc = fmaf(p0[grp * 16 + k], w6[(grp * 16 + k) * HID + j], acc);
  red[grp][j] = acc;
  __syncthreads();
  if (grp == 0) {
    float s = ((red[0][j] + red[1][j]) + (red[2][j] + red[3][j])) +
              ((red[4][j] + red[5][j]) + (red[6][j] + red[7][j])) + b6[j];
    gl[j] = fmaxf(s, 0.f);
  }
  __syncthreads();
  acc = 0.f;
#pragma unroll
  for (int k = 0; k < 16; ++k) acc = fmaf(gl[grp * 16 + k], w5[(grp * 16 + k) * HID + j], acc);
  red[grp][j] = acc;
  __syncthreads();
  if (grp == 0)
    gb5[j] = ((red[0][j] + red[1][j]) + (red[2][j] + red[3][j])) +
             ((red[4][j] + red[5][j]) + (red[6][j] + red[7][j])) + b5[j];
}

// ---------------- q GEMM: 32 rows/block, relu(relu(nv)@w5b + gb5) dot w8 + b8 ----------------

__global__ __launch_bounds__(256) void k_gq(const unsigned short* __restrict__ A,
                                            const unsigned short* __restrict__ Bt,
                                            const float* __restrict__ gb5,
                                            const float* __restrict__ w8,
                                            const float* __restrict__ b8,
                                            float* __restrict__ q, int n) {
  __shared__ float sq[2][32];
  int tid = threadIdx.x, lane = tid & 63, wave = tid >> 6;
  int lm = lane & 15, lk = lane >> 4;
  int row0 = blockIdx.x * 32 + (wave >> 1) * 16;
  int col0 = (wave & 1) * 64;
  int ra = min(row0 + lm, n - 1);
  f32x4 acc[4] = {};
#pragma unroll
  for (int ks = 0; ks < 4; ++ks) {
    bf16x8 a0 = *reinterpret_cast<const bf16x8*>(A + (size_t)ra * HID + ks * 32 + lk * 8);
#pragma unroll
    for (int ct = 0; ct < 4; ++ct) {
      bf16x8 bb = *reinterpret_cast<const bf16x8*>(Bt + (size_t)(col0 + ct * 16 + lm) * HID + ks * 32 + lk * 8);
      acc[ct] = __builtin_amdgcn_mfma_f32_16x16x32_bf16(a0, bb, acc[ct], 0, 0, 0);
    }
  }
  float ps[4];
#pragma unroll
  for (int r = 0; r < 4; ++r) {
    float p = 0.f;
#pragma unroll
    for (int ct = 0; ct < 4; ++ct) {
      int col = col0 + ct * 16 + lm;
      float v = fmaxf(acc[ct][r] + gb5[col], 0.f);
      p = fmaf(v, w8[col], p);
    }
    ps[r] = p;
  }
#pragma unroll
  for (int r = 0; r < 4; ++r) {
#pragma unroll
    for (int d = 1; d < 16; d <<= 1) ps[r] += __shfl_xor(ps[r], d);
  }
  if (lm == 0) {
#pragma unroll
    for (int r = 0; r < 4; ++r)
      sq[wave & 1][(wave >> 1) * 16 + lk * 4 + r] = ps[r];
  }
  __syncthreads();
  if (tid < 32) {
    int row = blockIdx.x * 32 + tid;
    if (row < n) q[row] = sq[0][tid] + sq[1][tid] + b8[0];
  }
}

// ---------------- launch ----------------

extern "C" void kernel_launch(void* const* d_in, const int* in_sizes, int n_in,
                              void* d_out, int out_size, void* d_ws, size_t ws_size,
                              hipStream_t stream) {
  const float* x   = (const float*)d_in[0];
  const int*   ei  = (const int*)d_in[1];
  const int*   sel = (const int*)d_in[2];
  const float* w1  = (const float*)d_in[3];
  const float* b1  = (const float*)d_in[4];
  const float* wc1 = (const float*)d_in[5];
  const float* bc1 = (const float*)d_in[6];
  const float* wc2 = (const float*)d_in[7];
  const float* bc2 = (const float*)d_in[8];
  const float* w2  = (const float*)d_in[9];
  const float* b2  = (const float*)d_in[10];
  const float* w5  = (const float*)d_in[11];
  const float* b5  = (const float*)d_in[12];
  const float* w6  = (const float*)d_in[13];
  const float* b6  = (const float*)d_in[14];
  const float* w8  = (const float*)d_in[15];
  const float* b8  = (const float*)d_in[16];

  int n = in_sizes[0] / 3;
  int e = in_sizes[1] / 2;
  const int* erow = ei;
  const int* ecol = ei + e;

  float* q  = (float*)d_out;
  float* nv = q + n;

  int g32 = (n + 31) / 32;          // 32-row GEMM grid
  int lgrid = (n * 64 + 255) / 256;
  int nbkt  = (n + 255) >> 8;
  int bgrid = (e + EPB - 1) / EPB;

  unsigned short* x1b = (unsigned short*)d_ws;            // [n,128] bf16
  unsigned short* x2b = x1b + (size_t)n * HID;            // [n,128] bf16
  unsigned short* x3b = x2b + (size_t)n * HID;            // [n,128] bf16
  unsigned char*  hb  = (unsigned char*)(x3b + (size_t)n * HID);  // [n,128] fp8
  unsigned short* nvr = (unsigned short*)(hb + (size_t)n * HID);  // [n,128] bf16
  unsigned short* wc1t = nvr + (size_t)n * HID;
  unsigned short* wc2t = wc1t + HID * HID;
  unsigned short* w5bt = wc2t + HID * HID;
  unsigned short* w2t  = w5bt + HID * HID;                // [128][384] bf16
  float* fw = (float*)(w2t + 384 * HID);
  float* dinv  = fw; fw += n;
  float* part  = fw; fw += (size_t)g32 * HID;
  float* gb5   = fw; fw += HID;
  int* iw = (int*)fw;
  int* gcnt = iw; iw += 256;
  int* offg = iw; iw += n;
  int* cnt  = iw; iw += n;
  unsigned* ebuf = (unsigned*)iw; iw += (size_t)nbkt * CAP;   // packed r | lc<<16
  int* csr = iw;                                              // nbkt*CAP ints

  // launch 1: zero the 256 bucket counters
  hipMemsetAsync(gcnt, 0, 256 * sizeof(int), stream);
  // launch 2: bucket sort | weight prep | lin1 (bf16)
  k_pre<<<bgrid + 384 + lgrid, 256, 0, stream>>>(x, w1, b1, wc1, wc2, w5 + HID * HID, w2,
                                                 wc1t, wc2t, w5bt, w2t, (unsigned*)x1b,
                                                 erow, ecol, gcnt, ebuf, e, bgrid, n);
  // launch 3: per-bucket CSR/deg/dinv || conv1 GEMM (hb = x1@wc1, fp8 out)
  k_csrconv<<<nbkt + g32, 256, 0, stream>>>(ebuf, gcnt, csr, offg, cnt, dinv,
                                            x1b, wc1t, hb, n, nbkt);
  // launch 4: agg1 (x2 = relu(...), bf16)
  k_agg<<<(n + 3) / 4, 256, 0, stream>>>((const uint4*)hb, dinv, offg, cnt, csr, bc1, (uint4*)x2b, n);
  // launch 5: conv2 GEMM (hb = x2@wc2, fp8)
  k_gconv<<<g32, 256, 0, stream>>>(x2b, wc2t, hb, n);
  // launch 6: agg2 (x3 = relu(...), bf16)
  k_agg<<<(n + 3) / 4, 256, 0, stream>>>((const uint4*)hb, dinv, offg, cnt, csr, bc2, (uint4*)x3b, n);
  // launch 7: nv = [x1|x2|x3]@w2 + b2 (f32 out + bf16 relu copy + pool partials)
  k_gnv<<<g32, 256, 0, stream>>>(x1b, x2b, x3b, w2t, b2, sel, nv, nvr, part, n);
  // launch 8: pool0 -> g -> gb5
  k_g<<<1, 1024, 0, stream>>>(part, g32, w6, b6, w5, b5, gb5);
  // launch 9: q = (relu(relu(nv)@w5b + gb5)) @ w8 + b8
  k_gq<<<g32, 256, 0, stream>>>(nvr, w5bt, gb5, w8, b8, q, n);
}

// Round 17
// 230.610 us; speedup vs baseline: 1.0964x; 1.0964x over previous
//
#include <hip/hip_runtime.h>

#define HID 128
#define CAP 8960   // per-bucket edge capacity (avg 8192, +8.5 sigma)
#define EPB 4096   // edges per bucket block

typedef __attribute__((ext_vector_type(8))) short bf16x8;
typedef __attribute__((ext_vector_type(4))) float f32x4;
typedef __attribute__((ext_vector_type(2))) float f32x2;

__device__ __forceinline__ unsigned short f2bf(float f) {
  unsigned u = __builtin_bit_cast(unsigned, f);
  u += 0x7FFFu + ((u >> 16) & 1u);  // RNE
  return (unsigned short)(u >> 16);
}
__device__ __forceinline__ float bflo(unsigned v) {
  return __builtin_bit_cast(float, v << 16);
}
__device__ __forceinline__ float bfhi(unsigned v) {
  return __builtin_bit_cast(float, v & 0xFFFF0000u);
}
__device__ __forceinline__ unsigned pck(float a, float b) {
  return (unsigned)f2bf(a) | ((unsigned)f2bf(b) << 16);
}

// ---------------- launch 2: bucket sort | prep weights | lin1 (role split) ----------------

__global__ __launch_bounds__(256) void k_pre(
    const float* __restrict__ x, const float* __restrict__ w1, const float* __restrict__ b1,
    const float* __restrict__ wc1, const float* __restrict__ wc2,
    const float* __restrict__ w5b, const float* __restrict__ w2,
    unsigned short* __restrict__ wc1t, unsigned short* __restrict__ wc2t,
    unsigned short* __restrict__ w5bt, unsigned short* __restrict__ w2t,
    unsigned* __restrict__ x1,
    const int* __restrict__ erow, const int* __restrict__ ecol,
    int* __restrict__ gcnt, unsigned* __restrict__ ebuf, int e, int bgrid, int n) {
  __shared__ int hist[256], base[256], cur[256];
  int b = blockIdx.x;
  int tid = threadIdx.x;
  if (b < bgrid) {
    // bucket sort by c>>8 (gcnt pre-zeroed via memset); packed r | lc<<16
    hist[tid] = 0;
    cur[tid] = 0;
    __syncthreads();
    int eb = b * EPB;
    int cc[16], rr[16];
#pragma unroll
    for (int k = 0; k < 16; ++k) {
      int i = eb + k * 256 + tid;
      if (i < e) {
        cc[k] = ecol[i];
        rr[k] = erow[i];
        atomicAdd(&hist[cc[k] >> 8], 1);
      } else {
        cc[k] = -1;
        rr[k] = 0;
      }
    }
    __syncthreads();
    if (hist[tid]) base[tid] = atomicAdd(&gcnt[tid], hist[tid]);
    __syncthreads();
#pragma unroll
    for (int k = 0; k < 16; ++k) {
      if (cc[k] >= 0) {
        int bk = cc[k] >> 8;
        int slot = base[bk] + atomicAdd(&cur[bk], 1);
        if (slot < CAP)
          ebuf[(size_t)bk * CAP + slot] = (unsigned)rr[k] | ((unsigned)(cc[k] & 255) << 16);
      }
    }
    return;
  }
  b -= bgrid;
  if (b < 384) {
    int idx = b * 256 + tid;
    if (idx < 16384) {
      int nn = idx >> 7, k = idx & 127;
      wc1t[idx] = f2bf(wc1[k * HID + nn]);
    } else if (idx < 32768) {
      int e2 = idx - 16384, nn = e2 >> 7, k = e2 & 127;
      wc2t[e2] = f2bf(wc2[k * HID + nn]);
    } else if (idx < 49152) {
      int e2 = idx - 32768, nn = e2 >> 7, k = e2 & 127;
      w5bt[e2] = f2bf(w5b[k * HID + nn]);
    } else if (idx < 98304) {
      int e2 = idx - 49152, nn = e2 / 384, k = e2 - nn * 384;
      w2t[e2] = f2bf(w2[k * HID + nn]);
    }
    return;
  }
  b -= 384;
  int idx = b * 256 + tid;
  if (idx >= n * 64) return;
  int i = idx >> 6, j = (idx & 63) * 2;
  float x0 = x[i * 3], xv1 = x[i * 3 + 1], xv2 = x[i * 3 + 2];
  float v0 = b1[j] + x0 * w1[j] + xv1 * w1[HID + j] + xv2 * w1[2 * HID + j];
  float v1 = b1[j + 1] + x0 * w1[j + 1] + xv1 * w1[HID + j + 1] + xv2 * w1[2 * HID + j + 1];
  x1[idx] = pck(v0, v1);
}

// ---------------- conv GEMM body: 64 rows x 128 cols (R15-proven) ----------------
// bf16 in/weights, fp8 e4m3 out.

__device__ __forceinline__ void gconv_body(int bid, const unsigned short* __restrict__ A,
                                           const unsigned short* __restrict__ Bt,
                                           unsigned char* __restrict__ C, int n) {
  int tid = threadIdx.x, lane = tid & 63, wave = tid >> 6;
  int lm = lane & 15, lk = lane >> 4;
  int row0 = bid * 64 + (wave >> 1) * 32;
  int col0 = (wave & 1) * 64;
  int ra = min(row0 + lm, n - 1), rb = min(row0 + 16 + lm, n - 1);
  f32x4 acc[2][4] = {};
#pragma unroll
  for (int ks = 0; ks < 4; ++ks) {
    bf16x8 a0 = *reinterpret_cast<const bf16x8*>(A + (size_t)ra * HID + ks * 32 + lk * 8);
    bf16x8 a1 = *reinterpret_cast<const bf16x8*>(A + (size_t)rb * HID + ks * 32 + lk * 8);
#pragma unroll
    for (int ct = 0; ct < 4; ++ct) {
      bf16x8 bb = *reinterpret_cast<const bf16x8*>(Bt + (size_t)(col0 + ct * 16 + lm) * HID + ks * 32 + lk * 8);
      acc[0][ct] = __builtin_amdgcn_mfma_f32_16x16x32_bf16(a0, bb, acc[0][ct], 0, 0, 0);
      acc[1][ct] = __builtin_amdgcn_mfma_f32_16x16x32_bf16(a1, bb, acc[1][ct], 0, 0, 0);
    }
  }
#pragma unroll
  for (int rt = 0; rt < 2; ++rt)
#pragma unroll
    for (int r = 0; r < 4; ++r) {
      int row = row0 + rt * 16 + lk * 4 + r;
      if (row < n) {
        int pa = __builtin_amdgcn_cvt_pk_fp8_f32(acc[rt][0][r], acc[rt][1][r], 0, false);
        int pb = __builtin_amdgcn_cvt_pk_fp8_f32(acc[rt][2][r], acc[rt][3][r], 0, false);
        size_t base = (size_t)row * HID + col0 + lm;
        C[base]      = (unsigned char)(pa & 0xFF);
        C[base + 16] = (unsigned char)((pa >> 8) & 0xFF);
        C[base + 32] = (unsigned char)(pb & 0xFF);
        C[base + 48] = (unsigned char)((pb >> 8) & 0xFF);
      }
    }
}

// ---------------- launch 3: per-bucket CSR build || conv1 GEMM (role split) ----------------

__global__ __launch_bounds__(256) void k_csrconv(
    const unsigned* __restrict__ ebuf, const int* __restrict__ gcnt,
    int* __restrict__ csr, int* __restrict__ offg, int* __restrict__ cnt,
    float* __restrict__ dinv,
    const unsigned short* __restrict__ A, const unsigned short* __restrict__ Bt,
    unsigned char* __restrict__ C, int n, int nbkt) {
  __shared__ int hist[256], scan[256], cur[256];
  int tid = threadIdx.x, b = blockIdx.x;
  if (b < nbkt) {
    int m = min(gcnt[b], CAP);
    hist[tid] = 0;
    cur[tid] = 0;
    __syncthreads();
    const unsigned* eb = ebuf + (size_t)b * CAP;
    for (int i = tid; i < m; i += 256) atomicAdd(&hist[(eb[i] >> 16) & 255], 1);
    __syncthreads();
    scan[tid] = hist[tid];
    __syncthreads();
    for (int d = 1; d < 256; d <<= 1) {
      int t = (tid >= d) ? scan[tid - d] : 0;
      __syncthreads();
      scan[tid] += t;
      __syncthreads();
    }
    scan[tid] -= hist[tid];  // exclusive
    int c = b * 256 + tid;
    if (c < n) {
      cnt[c] = hist[tid];
      offg[c] = b * CAP + scan[tid];
      dinv[c] = rsqrtf((float)hist[tid] + 1.0f);
    }
    __syncthreads();
    int* cb = csr + (size_t)b * CAP;
    for (int i = tid; i < m; i += 256) {
      unsigned eg = eb[i];
      int lc = (eg >> 16) & 255;
      cb[scan[lc] + atomicAdd(&cur[lc], 1)] = (int)(eg & 0xFFFF);
    }
    return;
  }
  gconv_body(b - nbkt, A, Bt, C, n);
}

__global__ void k_gconv(const unsigned short* __restrict__ A,
                        const unsigned short* __restrict__ Bt,
                        unsigned char* __restrict__ C, int n) {
  gconv_body(blockIdx.x, A, Bt, C, n);
}

// ---------------- GCN aggregation: wave/node, 8 groups x 8 lanes x 16B(fp8) ----------------
// 16 edges/iter, rotated csr/dinv prefetch (R15-proven).

__global__ __launch_bounds__(256) void k_agg(const uint4* __restrict__ h,
                                             const float* __restrict__ dinv,
                                             const int* __restrict__ offg,
                                             const int* __restrict__ cnt,
                                             const int* __restrict__ csr,
                                             const float* __restrict__ bias,
                                             uint4* __restrict__ out, int n) {
  int wave = threadIdx.x >> 6, lane = threadIdx.x & 63;
  int c = blockIdx.x * 4 + wave;
  if (c >= n) return;
  int g = lane >> 3, cp = lane & 7;
  float dc = dinv[c];
  float acc[16];
  {
    uint4 v = h[(size_t)c * 8 + cp];
    float ws = (g == 0) ? dc : 0.f;  // self-loop term dc*h[c]
    f32x2 p;
    p = __builtin_amdgcn_cvt_pk_f32_fp8((int)v.x, false); acc[0] = p.x * ws; acc[1] = p.y * ws;
    p = __builtin_amdgcn_cvt_pk_f32_fp8((int)v.x, true);  acc[2] = p.x * ws; acc[3] = p.y * ws;
    p = __builtin_amdgcn_cvt_pk_f32_fp8((int)v.y, false); acc[4] = p.x * ws; acc[5] = p.y * ws;
    p = __builtin_amdgcn_cvt_pk_f32_fp8((int)v.y, true);  acc[6] = p.x * ws; acc[7] = p.y * ws;
    p = __builtin_amdgcn_cvt_pk_f32_fp8((int)v.z, false); acc[8] = p.x * ws; acc[9] = p.y * ws;
    p = __builtin_amdgcn_cvt_pk_f32_fp8((int)v.z, true);  acc[10] = p.x * ws; acc[11] = p.y * ws;
    p = __builtin_amdgcn_cvt_pk_f32_fp8((int)v.w, false); acc[12] = p.x * ws; acc[13] = p.y * ws;
    p = __builtin_amdgcn_cvt_pk_f32_fp8((int)v.w, true);  acc[14] = p.x * ws; acc[15] = p.y * ws;
  }
  int s = offg[c], t = s + cnt[c];
  int j0 = s + g, j1 = s + 8 + g;
  bool v0 = j0 < t, v1 = j1 < t;
  int r0 = csr[v0 ? j0 : s];
  int r1 = csr[v1 ? j1 : s];
  float w0 = v0 ? dinv[r0] : 0.f;
  float w1 = v1 ? dinv[r1] : 0.f;
  for (int idx = s; idx < t; idx += 16) {
    uint4 h0 = h[(size_t)r0 * 8 + cp];
    uint4 h1 = h[(size_t)r1 * 8 + cp];
    int jn0 = idx + 16 + g, jn1 = idx + 24 + g;
    bool nv0 = jn0 < t, nv1 = jn1 < t;
    int nr0 = csr[nv0 ? jn0 : s];
    int nr1 = csr[nv1 ? jn1 : s];
    float nw0 = nv0 ? dinv[nr0] : 0.f;
    float nw1 = nv1 ? dinv[nr1] : 0.f;
    f32x2 p;
#define ACC8(vv, ww)                                                                     \
    p = __builtin_amdgcn_cvt_pk_f32_fp8((int)vv.x, false); acc[0] = fmaf(p.x, ww, acc[0]); acc[1] = fmaf(p.y, ww, acc[1]); \
    p = __builtin_amdgcn_cvt_pk_f32_fp8((int)vv.x, true);  acc[2] = fmaf(p.x, ww, acc[2]); acc[3] = fmaf(p.y, ww, acc[3]); \
    p = __builtin_amdgcn_cvt_pk_f32_fp8((int)vv.y, false); acc[4] = fmaf(p.x, ww, acc[4]); acc[5] = fmaf(p.y, ww, acc[5]); \
    p = __builtin_amdgcn_cvt_pk_f32_fp8((int)vv.y, true);  acc[6] = fmaf(p.x, ww, acc[6]); acc[7] = fmaf(p.y, ww, acc[7]); \
    p = __builtin_amdgcn_cvt_pk_f32_fp8((int)vv.z, false); acc[8] = fmaf(p.x, ww, acc[8]); acc[9] = fmaf(p.y, ww, acc[9]); \
    p = __builtin_amdgcn_cvt_pk_f32_fp8((int)vv.z, true);  acc[10] = fmaf(p.x, ww, acc[10]); acc[11] = fmaf(p.y, ww, acc[11]); \
    p = __builtin_amdgcn_cvt_pk_f32_fp8((int)vv.w, false); acc[12] = fmaf(p.x, ww, acc[12]); acc[13] = fmaf(p.y, ww, acc[13]); \
    p = __builtin_amdgcn_cvt_pk_f32_fp8((int)vv.w, true);  acc[14] = fmaf(p.x, ww, acc[14]); acc[15] = fmaf(p.y, ww, acc[15]);
    ACC8(h0, w0)
    ACC8(h1, w1)
#undef ACC8
    r0 = nr0; r1 = nr1; w0 = nw0; w1 = nw1;
  }
#pragma unroll
  for (int i = 0; i < 16; ++i) {
    acc[i] += __shfl_xor(acc[i], 8);
    acc[i] += __shfl_xor(acc[i], 16);
    acc[i] += __shfl_xor(acc[i], 32);
  }
  if (g == 0) {
    int cb = cp * 16;
    uint4 o1, o2;
    o1.x = pck(fmaxf(fmaf(acc[0], dc, bias[cb + 0]), 0.f), fmaxf(fmaf(acc[1], dc, bias[cb + 1]), 0.f));
    o1.y = pck(fmaxf(fmaf(acc[2], dc, bias[cb + 2]), 0.f), fmaxf(fmaf(acc[3], dc, bias[cb + 3]), 0.f));
    o1.z = pck(fmaxf(fmaf(acc[4], dc, bias[cb + 4]), 0.f), fmaxf(fmaf(acc[5], dc, bias[cb + 5]), 0.f));
    o1.w = pck(fmaxf(fmaf(acc[6], dc, bias[cb + 6]), 0.f), fmaxf(fmaf(acc[7], dc, bias[cb + 7]), 0.f));
    o2.x = pck(fmaxf(fmaf(acc[8], dc, bias[cb + 8]), 0.f), fmaxf(fmaf(acc[9], dc, bias[cb + 9]), 0.f));
    o2.y = pck(fmaxf(fmaf(acc[10], dc, bias[cb + 10]), 0.f), fmaxf(fmaf(acc[11], dc, bias[cb + 11]), 0.f));
    o2.z = pck(fmaxf(fmaf(acc[12], dc, bias[cb + 12]), 0.f), fmaxf(fmaf(acc[13], dc, bias[cb + 13]), 0.f));
    o2.w = pck(fmaxf(fmaf(acc[14], dc, bias[cb + 14]), 0.f), fmaxf(fmaf(acc[15], dc, bias[cb + 15]), 0.f));
    out[(size_t)c * 16 + cp * 2] = o1;
    out[(size_t)c * 16 + cp * 2 + 1] = o2;
  }
}

// ---------------- nv GEMM: 64 rows x 64 cols per block (grid 2x for occupancy) ----------------
// writes nv f32 (output), relu(nv) bf16 (for q GEMM), masked col-partials (pool).

__global__ __launch_bounds__(256) void k_gnv(const unsigned short* __restrict__ A1,
                                             const unsigned short* __restrict__ A2,
                                             const unsigned short* __restrict__ A3,
                                             const unsigned short* __restrict__ Bt,
                                             const float* __restrict__ b2,
                                             const int* __restrict__ sel,
                                             float* __restrict__ nv,
                                             unsigned short* __restrict__ nvr,
                                             float* __restrict__ part, int n) {
  __shared__ float spart[HID];
  int tid = threadIdx.x, lane = tid & 63, wave = tid >> 6;
  if (tid < HID) spart[tid] = 0.f;
  int lm = lane & 15, lk = lane >> 4;
  int bid = blockIdx.x;
  int row0 = (bid >> 1) * 64 + (wave >> 1) * 32;
  int col0 = (bid & 1) * 64 + (wave & 1) * 32;
  int ra = min(row0 + lm, n - 1), rbr = min(row0 + 16 + lm, n - 1);
  f32x4 acc[2][2] = {};
  const unsigned short* As[3] = {A1, A2, A3};
#pragma unroll
  for (int kb = 0; kb < 3; ++kb) {
    const unsigned short* A = As[kb];
#pragma unroll
    for (int ks = 0; ks < 4; ++ks) {
      bf16x8 a0 = *reinterpret_cast<const bf16x8*>(A + (size_t)ra * HID + ks * 32 + lk * 8);
      bf16x8 a1 = *reinterpret_cast<const bf16x8*>(A + (size_t)rbr * HID + ks * 32 + lk * 8);
#pragma unroll
      for (int ct = 0; ct < 2; ++ct) {
        bf16x8 bb = *reinterpret_cast<const bf16x8*>(
            Bt + (size_t)(col0 + ct * 16 + lm) * 384 + kb * 128 + ks * 32 + lk * 8);
        acc[0][ct] = __builtin_amdgcn_mfma_f32_16x16x32_bf16(a0, bb, acc[0][ct], 0, 0, 0);
        acc[1][ct] = __builtin_amdgcn_mfma_f32_16x16x32_bf16(a1, bb, acc[1][ct], 0, 0, 0);
      }
    }
  }
  float psum[2] = {0.f, 0.f};
#pragma unroll
  for (int rt = 0; rt < 2; ++rt)
#pragma unroll
    for (int r = 0; r < 4; ++r) {
      int row = row0 + rt * 16 + lk * 4 + r;
      if (row < n) {
        float m = (sel[row] == 0) ? 1.f : 0.f;
#pragma unroll
        for (int ct = 0; ct < 2; ++ct) {
          int col = col0 + ct * 16 + lm;
          float v = acc[rt][ct][r] + b2[col];
          nv[(size_t)row * HID + col] = v;
          nvr[(size_t)row * HID + col] = f2bf(fmaxf(v, 0.f));
          psum[ct] = fmaf(m, v, psum[ct]);
        }
      }
    }
#pragma unroll
  for (int ct = 0; ct < 2; ++ct) {
    psum[ct] += __shfl_xor(psum[ct], 16);
    psum[ct] += __shfl_xor(psum[ct], 32);
  }
  __syncthreads();
  if (lk == 0) {
#pragma unroll
    for (int ct = 0; ct < 2; ++ct) atomicAdd(&spart[col0 + ct * 16 + lm], psum[ct]);
  }
  __syncthreads();
  if (tid < HID) part[(size_t)bid * HID + tid] = spart[tid];
}

// ---------------- parallel pool-final + g + gb5 (1 block x 1024 thr) ----------------

__global__ __launch_bounds__(1024) void k_g(const float* __restrict__ part, int nblk,
                                            const float* __restrict__ w6, const float* __restrict__ b6,
                                            const float* __restrict__ w5, const float* __restrict__ b5,
                                            float* __restrict__ gb5) {
  __shared__ float red[8][HID];
  __shared__ float p0[HID], gl[HID];
  int t = threadIdx.x, j = t & 127, grp = t >> 7;
  float a0 = 0.f, a1 = 0.f, a2 = 0.f, a3 = 0.f;
  int r = grp;
  for (; r + 32 <= nblk; r += 32) {
    a0 += part[(size_t)(r)*HID + j];
    a1 += part[(size_t)(r + 8) * HID + j];
    a2 += part[(size_t)(r + 16) * HID + j];
    a3 += part[(size_t)(r + 24) * HID + j];
  }
  for (; r < nblk; r += 8) a0 += part[(size_t)r * HID + j];
  red[grp][j] = (a0 + a1) + (a2 + a3);
  __syncthreads();
  if (grp == 0)
    p0[j] = ((red[0][j] + red[1][j]) + (red[2][j] + red[3][j])) +
            ((red[4][j] + red[5][j]) + (red[6][j] + red[7][j]));
  __syncthreads();
  float acc = 0.f;
#pragma unroll
  for (int k = 0; k < 16; ++k) acc = fmaf(p0[grp * 16 + k], w6[(grp * 16 + k) * HID + j], acc);
  red[grp][j] = acc;
  __syncthreads();
  if (grp == 0) {
    float s = ((red[0][j] + red[1][j]) + (red[2][j] + red[3][j])) +
              ((red[4][j] + red[5][j]) + (red[6][j] + red[7][j])) + b6[j];
    gl[j] = fmaxf(s, 0.f);
  }
  __syncthreads();
  acc = 0.f;
#pragma unroll
  for (int k = 0; k < 16; ++k) acc = fmaf(gl[grp * 16 + k], w5[(grp * 16 + k) * HID + j], acc);
  red[grp][j] = acc;
  __syncthreads();
  if (grp == 0)
    gb5[j] = ((red[0][j] + red[1][j]) + (red[2][j] + red[3][j])) +
             ((red[4][j] + red[5][j]) + (red[6][j] + red[7][j])) + b5[j];
}

// ---------------- q GEMM: 64 rows x 128 cols (R15-proven) ----------------

__global__ __launch_bounds__(256) void k_gq(const unsigned short* __restrict__ A,
                                            const unsigned short* __restrict__ Bt,
                                            const float* __restrict__ gb5,
                                            const float* __restrict__ w8,
                                            const float* __restrict__ b8,
                                            float* __restrict__ q, int n) {
  __shared__ float sq[2][64];
  int tid = threadIdx.x, lane = tid & 63, wave = tid >> 6;
  int lm = lane & 15, lk = lane >> 4;
  int row0 = blockIdx.x * 64 + (wave >> 1) * 32;
  int col0 = (wave & 1) * 64;
  int ra = min(row0 + lm, n - 1), rb = min(row0 + 16 + lm, n - 1);
  f32x4 acc[2][4] = {};
#pragma unroll
  for (int ks = 0; ks < 4; ++ks) {
    bf16x8 a0 = *reinterpret_cast<const bf16x8*>(A + (size_t)ra * HID + ks * 32 + lk * 8);
    bf16x8 a1 = *reinterpret_cast<const bf16x8*>(A + (size_t)rb * HID + ks * 32 + lk * 8);
#pragma unroll
    for (int ct = 0; ct < 4; ++ct) {
      bf16x8 bb = *reinterpret_cast<const bf16x8*>(Bt + (size_t)(col0 + ct * 16 + lm) * HID + ks * 32 + lk * 8);
      acc[0][ct] = __builtin_amdgcn_mfma_f32_16x16x32_bf16(a0, bb, acc[0][ct], 0, 0, 0);
      acc[1][ct] = __builtin_amdgcn_mfma_f32_16x16x32_bf16(a1, bb, acc[1][ct], 0, 0, 0);
    }
  }
  float ps[2][4];
#pragma unroll
  for (int rt = 0; rt < 2; ++rt)
#pragma unroll
    for (int r = 0; r < 4; ++r) {
      float p = 0.f;
#pragma unroll
      for (int ct = 0; ct < 4; ++ct) {
        int col = col0 + ct * 16 + lm;
        float v = fmaxf(acc[rt][ct][r] + gb5[col], 0.f);
        p = fmaf(v, w8[col], p);
      }
      ps[rt][r] = p;
    }
#pragma unroll
  for (int rt = 0; rt < 2; ++rt)
#pragma unroll
    for (int r = 0; r < 4; ++r) {
#pragma unroll
      for (int d = 1; d < 16; d <<= 1) ps[rt][r] += __shfl_xor(ps[rt][r], d);
    }
  if (lm == 0) {
#pragma unroll
    for (int rt = 0; rt < 2; ++rt)
#pragma unroll
      for (int r = 0; r < 4; ++r)
        sq[wave & 1][(wave >> 1) * 32 + rt * 16 + lk * 4 + r] = ps[rt][r];
  }
  __syncthreads();
  if (tid < 64) {
    int row = blockIdx.x * 64 + tid;
    if (row < n) q[row] = sq[0][tid] + sq[1][tid] + b8[0];
  }
}

// ---------------- launch ----------------

extern "C" void kernel_launch(void* const* d_in, const int* in_sizes, int n_in,
                              void* d_out, int out_size, void* d_ws, size_t ws_size,
                              hipStream_t stream) {
  const float* x   = (const float*)d_in[0];
  const int*   ei  = (const int*)d_in[1];
  const int*   sel = (const int*)d_in[2];
  const float* w1  = (const float*)d_in[3];
  const float* b1  = (const float*)d_in[4];
  const float* wc1 = (const float*)d_in[5];
  const float* bc1 = (const float*)d_in[6];
  const float* wc2 = (const float*)d_in[7];
  const float* bc2 = (const float*)d_in[8];
  const float* w2  = (const float*)d_in[9];
  const float* b2  = (const float*)d_in[10];
  const float* w5  = (const float*)d_in[11];
  const float* b5  = (const float*)d_in[12];
  const float* w6  = (const float*)d_in[13];
  const float* b6  = (const float*)d_in[14];
  const float* w8  = (const float*)d_in[15];
  const float* b8  = (const float*)d_in[16];

  int n = in_sizes[0] / 3;
  int e = in_sizes[1] / 2;
  const int* erow = ei;
  const int* ecol = ei + e;

  float* q  = (float*)d_out;
  float* nv = q + n;

  int g64 = (n + 63) / 64;
  int lgrid = (n * 64 + 255) / 256;
  int nbkt  = (n + 255) >> 8;
  int bgrid = (e + EPB - 1) / EPB;

  unsigned short* x1b = (unsigned short*)d_ws;            // [n,128] bf16
  unsigned short* x2b = x1b + (size_t)n * HID;            // [n,128] bf16
  unsigned short* x3b = x2b + (size_t)n * HID;            // [n,128] bf16
  unsigned char*  hb  = (unsigned char*)(x3b + (size_t)n * HID);  // [n,128] fp8
  unsigned short* nvr = (unsigned short*)(hb + (size_t)n * HID);  // [n,128] bf16
  unsigned short* wc1t = nvr + (size_t)n * HID;
  unsigned short* wc2t = wc1t + HID * HID;
  unsigned short* w5bt = wc2t + HID * HID;
  unsigned short* w2t  = w5bt + HID * HID;                // [128][384] bf16
  float* fw = (float*)(w2t + 384 * HID);
  float* dinv  = fw; fw += n;
  float* part  = fw; fw += (size_t)g64 * 2 * HID;
  float* gb5   = fw; fw += HID;
  int* iw = (int*)fw;
  int* gcnt = iw; iw += 256;
  int* offg = iw; iw += n;
  int* cnt  = iw; iw += n;
  unsigned* ebuf = (unsigned*)iw; iw += (size_t)nbkt * CAP;   // packed r | lc<<16
  int* csr = iw;                                              // nbkt*CAP ints

  // launch 1: zero the 256 bucket counters
  hipMemsetAsync(gcnt, 0, 256 * sizeof(int), stream);
  // launch 2: bucket sort | weight prep | lin1 (bf16)
  k_pre<<<bgrid + 384 + lgrid, 256, 0, stream>>>(x, w1, b1, wc1, wc2, w5 + HID * HID, w2,
                                                 wc1t, wc2t, w5bt, w2t, (unsigned*)x1b,
                                                 erow, ecol, gcnt, ebuf, e, bgrid, n);
  // launch 3: per-bucket CSR/deg/dinv || conv1 GEMM (hb = x1@wc1, fp8 out)
  k_csrconv<<<nbkt + g64, 256, 0, stream>>>(ebuf, gcnt, csr, offg, cnt, dinv,
                                            x1b, wc1t, hb, n, nbkt);
  // launch 4: agg1 (x2 = relu(...), bf16)
  k_agg<<<(n + 3) / 4, 256, 0, stream>>>((const uint4*)hb, dinv, offg, cnt, csr, bc1, (uint4*)x2b, n);
  // launch 5: conv2 GEMM (hb = x2@wc2, fp8)
  k_gconv<<<g64, 256, 0, stream>>>(x2b, wc2t, hb, n);
  // launch 6: agg2 (x3 = relu(...), bf16)
  k_agg<<<(n + 3) / 4, 256, 0, stream>>>((const uint4*)hb, dinv, offg, cnt, csr, bc2, (uint4*)x3b, n);
  // launch 7: nv = [x1|x2|x3]@w2 + b2 (64x64 tiles; f32 out + bf16 relu copy + pool partials)
  k_gnv<<<g64 * 2, 256, 0, stream>>>(x1b, x2b, x3b, w2t, b2, sel, nv, nvr, part, n);
  // launch 8: pool0 -> g -> gb5
  k_g<<<1, 1024, 0, stream>>>(part, g64 * 2, w6, b6, w5, b5, gb5);
  // launch 9: q = (relu(relu(nv)@w5b + gb5)) @ w8 + b8
  k_gq<<<g64, 256, 0, stream>>>(nvr, w5bt, gb5, w8, b8, q, n);
}

// Round 18
// 218.319 us; speedup vs baseline: 1.1581x; 1.0563x over previous
//
#include <hip/hip_runtime.h>

#define HID 128
#define CAP 8960   // per-bucket edge capacity (avg 8192, +8.5 sigma)
#define EPB 4096   // edges per bucket block

typedef __attribute__((ext_vector_type(8))) short bf16x8;
typedef __attribute__((ext_vector_type(4))) float f32x4;
typedef __attribute__((ext_vector_type(2))) float f32x2;

__device__ __forceinline__ unsigned short f2bf(float f) {
  unsigned u = __builtin_bit_cast(unsigned, f);
  u += 0x7FFFu + ((u >> 16) & 1u);  // RNE
  return (unsigned short)(u >> 16);
}
__device__ __forceinline__ float bflo(unsigned v) {
  return __builtin_bit_cast(float, v << 16);
}
__device__ __forceinline__ float bfhi(unsigned v) {
  return __builtin_bit_cast(float, v & 0xFFFF0000u);
}
__device__ __forceinline__ unsigned pck(float a, float b) {
  return (unsigned)f2bf(a) | ((unsigned)f2bf(b) << 16);
}

// ---------------- launch 2: bucket sort | prep weights | lin1 (role split) ----------------

__global__ __launch_bounds__(256) void k_pre(
    const float* __restrict__ x, const float* __restrict__ w1, const float* __restrict__ b1,
    const float* __restrict__ wc1, const float* __restrict__ wc2,
    const float* __restrict__ w5b, const float* __restrict__ w2,
    unsigned short* __restrict__ wc1t, unsigned short* __restrict__ wc2t,
    unsigned short* __restrict__ w5bt, unsigned short* __restrict__ w2t,
    unsigned* __restrict__ x1,
    const int* __restrict__ erow, const int* __restrict__ ecol,
    int* __restrict__ gcnt, unsigned* __restrict__ ebuf, int e, int bgrid, int n) {
  __shared__ int hist[256], base[256], cur[256];
  int b = blockIdx.x;
  int tid = threadIdx.x;
  if (b < bgrid) {
    // bucket sort by c>>8 (gcnt pre-zeroed via memset); packed r | lc<<16
    hist[tid] = 0;
    cur[tid] = 0;
    __syncthreads();
    int eb = b * EPB;
    int cc[16], rr[16];
#pragma unroll
    for (int k = 0; k < 16; ++k) {
      int i = eb + k * 256 + tid;
      if (i < e) {
        cc[k] = ecol[i];
        rr[k] = erow[i];
        atomicAdd(&hist[cc[k] >> 8], 1);
      } else {
        cc[k] = -1;
        rr[k] = 0;
      }
    }
    __syncthreads();
    if (hist[tid]) base[tid] = atomicAdd(&gcnt[tid], hist[tid]);
    __syncthreads();
#pragma unroll
    for (int k = 0; k < 16; ++k) {
      if (cc[k] >= 0) {
        int bk = cc[k] >> 8;
        int slot = base[bk] + atomicAdd(&cur[bk], 1);
        if (slot < CAP)
          ebuf[(size_t)bk * CAP + slot] = (unsigned)rr[k] | ((unsigned)(cc[k] & 255) << 16);
      }
    }
    return;
  }
  b -= bgrid;
  if (b < 384) {
    int idx = b * 256 + tid;
    if (idx < 16384) {
      int nn = idx >> 7, k = idx & 127;
      wc1t[idx] = f2bf(wc1[k * HID + nn]);
    } else if (idx < 32768) {
      int e2 = idx - 16384, nn = e2 >> 7, k = e2 & 127;
      wc2t[e2] = f2bf(wc2[k * HID + nn]);
    } else if (idx < 49152) {
      int e2 = idx - 32768, nn = e2 >> 7, k = e2 & 127;
      w5bt[e2] = f2bf(w5b[k * HID + nn]);
    } else if (idx < 98304) {
      int e2 = idx - 49152, nn = e2 / 384, k = e2 - nn * 384;
      w2t[e2] = f2bf(w2[k * HID + nn]);
    }
    return;
  }
  b -= 384;
  int idx = b * 256 + tid;
  if (idx >= n * 64) return;
  int i = idx >> 6, j = (idx & 63) * 2;
  float x0 = x[i * 3], xv1 = x[i * 3 + 1], xv2 = x[i * 3 + 2];
  float v0 = b1[j] + x0 * w1[j] + xv1 * w1[HID + j] + xv2 * w1[2 * HID + j];
  float v1 = b1[j + 1] + x0 * w1[j + 1] + xv1 * w1[HID + j + 1] + xv2 * w1[2 * HID + j + 1];
  x1[idx] = pck(v0, v1);
}

// ---------------- conv GEMM body: 64 rows x 128 cols (R15-proven) ----------------
// bf16 in/weights, fp8 e4m3 out.

__device__ __forceinline__ void gconv_body(int bid, const unsigned short* __restrict__ A,
                                           const unsigned short* __restrict__ Bt,
                                           unsigned char* __restrict__ C, int n) {
  int tid = threadIdx.x, lane = tid & 63, wave = tid >> 6;
  int lm = lane & 15, lk = lane >> 4;
  int row0 = bid * 64 + (wave >> 1) * 32;
  int col0 = (wave & 1) * 64;
  int ra = min(row0 + lm, n - 1), rb = min(row0 + 16 + lm, n - 1);
  f32x4 acc[2][4] = {};
#pragma unroll
  for (int ks = 0; ks < 4; ++ks) {
    bf16x8 a0 = *reinterpret_cast<const bf16x8*>(A + (size_t)ra * HID + ks * 32 + lk * 8);
    bf16x8 a1 = *reinterpret_cast<const bf16x8*>(A + (size_t)rb * HID + ks * 32 + lk * 8);
#pragma unroll
    for (int ct = 0; ct < 4; ++ct) {
      bf16x8 bb = *reinterpret_cast<const bf16x8*>(Bt + (size_t)(col0 + ct * 16 + lm) * HID + ks * 32 + lk * 8);
      acc[0][ct] = __builtin_amdgcn_mfma_f32_16x16x32_bf16(a0, bb, acc[0][ct], 0, 0, 0);
      acc[1][ct] = __builtin_amdgcn_mfma_f32_16x16x32_bf16(a1, bb, acc[1][ct], 0, 0, 0);
    }
  }
#pragma unroll
  for (int rt = 0; rt < 2; ++rt)
#pragma unroll
    for (int r = 0; r < 4; ++r) {
      int row = row0 + rt * 16 + lk * 4 + r;
      if (row < n) {
        int pa = __builtin_amdgcn_cvt_pk_fp8_f32(acc[rt][0][r], acc[rt][1][r], 0, false);
        int pb = __builtin_amdgcn_cvt_pk_fp8_f32(acc[rt][2][r], acc[rt][3][r], 0, false);
        size_t base = (size_t)row * HID + col0 + lm;
        C[base]      = (unsigned char)(pa & 0xFF);
        C[base + 16] = (unsigned char)((pa >> 8) & 0xFF);
        C[base + 32] = (unsigned char)(pb & 0xFF);
        C[base + 48] = (unsigned char)((pb >> 8) & 0xFF);
      }
    }
}

// ---------------- launch 3: per-bucket CSR build || conv1 GEMM (role split) ----------------

__global__ __launch_bounds__(256) void k_csrconv(
    const unsigned* __restrict__ ebuf, const int* __restrict__ gcnt,
    int* __restrict__ csr, int* __restrict__ offg, int* __restrict__ cnt,
    float* __restrict__ dinv,
    const unsigned short* __restrict__ A, const unsigned short* __restrict__ Bt,
    unsigned char* __restrict__ C, int n, int nbkt) {
  __shared__ int hist[256], scan[256], cur[256];
  int tid = threadIdx.x, b = blockIdx.x;
  if (b < nbkt) {
    int m = min(gcnt[b], CAP);
    hist[tid] = 0;
    cur[tid] = 0;
    __syncthreads();
    const unsigned* eb = ebuf + (size_t)b * CAP;
    for (int i = tid; i < m; i += 256) atomicAdd(&hist[(eb[i] >> 16) & 255], 1);
    __syncthreads();
    scan[tid] = hist[tid];
    __syncthreads();
    for (int d = 1; d < 256; d <<= 1) {
      int t = (tid >= d) ? scan[tid - d] : 0;
      __syncthreads();
      scan[tid] += t;
      __syncthreads();
    }
    scan[tid] -= hist[tid];  // exclusive
    int c = b * 256 + tid;
    if (c < n) {
      cnt[c] = hist[tid];
      offg[c] = b * CAP + scan[tid];
      dinv[c] = rsqrtf((float)hist[tid] + 1.0f);
    }
    __syncthreads();
    int* cb = csr + (size_t)b * CAP;
    for (int i = tid; i < m; i += 256) {
      unsigned eg = eb[i];
      int lc = (eg >> 16) & 255;
      cb[scan[lc] + atomicAdd(&cur[lc], 1)] = (int)(eg & 0xFFFF);
    }
    return;
  }
  gconv_body(b - nbkt, A, Bt, C, n);
}

__global__ void k_gconv(const unsigned short* __restrict__ A,
                        const unsigned short* __restrict__ Bt,
                        unsigned char* __restrict__ C, int n) {
  gconv_body(blockIdx.x, A, Bt, C, n);
}

// ---------------- GCN aggregation: wave/node, 8 groups x 8 lanes x 16B(fp8) ----------------
// 16 edges/iter, rotated csr/dinv prefetch (R15-proven).

__global__ __launch_bounds__(256) void k_agg(const uint4* __restrict__ h,
                                             const float* __restrict__ dinv,
                                             const int* __restrict__ offg,
                                             const int* __restrict__ cnt,
                                             const int* __restrict__ csr,
                                             const float* __restrict__ bias,
                                             uint4* __restrict__ out, int n) {
  int wave = threadIdx.x >> 6, lane = threadIdx.x & 63;
  int c = blockIdx.x * 4 + wave;
  if (c >= n) return;
  int g = lane >> 3, cp = lane & 7;
  float dc = dinv[c];
  float acc[16];
  {
    uint4 v = h[(size_t)c * 8 + cp];
    float ws = (g == 0) ? dc : 0.f;  // self-loop term dc*h[c]
    f32x2 p;
    p = __builtin_amdgcn_cvt_pk_f32_fp8((int)v.x, false); acc[0] = p.x * ws; acc[1] = p.y * ws;
    p = __builtin_amdgcn_cvt_pk_f32_fp8((int)v.x, true);  acc[2] = p.x * ws; acc[3] = p.y * ws;
    p = __builtin_amdgcn_cvt_pk_f32_fp8((int)v.y, false); acc[4] = p.x * ws; acc[5] = p.y * ws;
    p = __builtin_amdgcn_cvt_pk_f32_fp8((int)v.y, true);  acc[6] = p.x * ws; acc[7] = p.y * ws;
    p = __builtin_amdgcn_cvt_pk_f32_fp8((int)v.z, false); acc[8] = p.x * ws; acc[9] = p.y * ws;
    p = __builtin_amdgcn_cvt_pk_f32_fp8((int)v.z, true);  acc[10] = p.x * ws; acc[11] = p.y * ws;
    p = __builtin_amdgcn_cvt_pk_f32_fp8((int)v.w, false); acc[12] = p.x * ws; acc[13] = p.y * ws;
    p = __builtin_amdgcn_cvt_pk_f32_fp8((int)v.w, true);  acc[14] = p.x * ws; acc[15] = p.y * ws;
  }
  int s = offg[c], t = s + cnt[c];
  int j0 = s + g, j1 = s + 8 + g;
  bool v0 = j0 < t, v1 = j1 < t;
  int r0 = csr[v0 ? j0 : s];
  int r1 = csr[v1 ? j1 : s];
  float w0 = v0 ? dinv[r0] : 0.f;
  float w1 = v1 ? dinv[r1] : 0.f;
  for (int idx = s; idx < t; idx += 16) {
    uint4 h0 = h[(size_t)r0 * 8 + cp];
    uint4 h1 = h[(size_t)r1 * 8 + cp];
    int jn0 = idx + 16 + g, jn1 = idx + 24 + g;
    bool nv0 = jn0 < t, nv1 = jn1 < t;
    int nr0 = csr[nv0 ? jn0 : s];
    int nr1 = csr[nv1 ? jn1 : s];
    float nw0 = nv0 ? dinv[nr0] : 0.f;
    float nw1 = nv1 ? dinv[nr1] : 0.f;
    f32x2 p;
#define ACC8(vv, ww)                                                                     \
    p = __builtin_amdgcn_cvt_pk_f32_fp8((int)vv.x, false); acc[0] = fmaf(p.x, ww, acc[0]); acc[1] = fmaf(p.y, ww, acc[1]); \
    p = __builtin_amdgcn_cvt_pk_f32_fp8((int)vv.x, true);  acc[2] = fmaf(p.x, ww, acc[2]); acc[3] = fmaf(p.y, ww, acc[3]); \
    p = __builtin_amdgcn_cvt_pk_f32_fp8((int)vv.y, false); acc[4] = fmaf(p.x, ww, acc[4]); acc[5] = fmaf(p.y, ww, acc[5]); \
    p = __builtin_amdgcn_cvt_pk_f32_fp8((int)vv.y, true);  acc[6] = fmaf(p.x, ww, acc[6]); acc[7] = fmaf(p.y, ww, acc[7]); \
    p = __builtin_amdgcn_cvt_pk_f32_fp8((int)vv.z, false); acc[8] = fmaf(p.x, ww, acc[8]); acc[9] = fmaf(p.y, ww, acc[9]); \
    p = __builtin_amdgcn_cvt_pk_f32_fp8((int)vv.z, true);  acc[10] = fmaf(p.x, ww, acc[10]); acc[11] = fmaf(p.y, ww, acc[11]); \
    p = __builtin_amdgcn_cvt_pk_f32_fp8((int)vv.w, false); acc[12] = fmaf(p.x, ww, acc[12]); acc[13] = fmaf(p.y, ww, acc[13]); \
    p = __builtin_amdgcn_cvt_pk_f32_fp8((int)vv.w, true);  acc[14] = fmaf(p.x, ww, acc[14]); acc[15] = fmaf(p.y, ww, acc[15]);
    ACC8(h0, w0)
    ACC8(h1, w1)
#undef ACC8
    r0 = nr0; r1 = nr1; w0 = nw0; w1 = nw1;
  }
#pragma unroll
  for (int i = 0; i < 16; ++i) {
    acc[i] += __shfl_xor(acc[i], 8);
    acc[i] += __shfl_xor(acc[i], 16);
    acc[i] += __shfl_xor(acc[i], 32);
  }
  if (g == 0) {
    int cb = cp * 16;
    uint4 o1, o2;
    o1.x = pck(fmaxf(fmaf(acc[0], dc, bias[cb + 0]), 0.f), fmaxf(fmaf(acc[1], dc, bias[cb + 1]), 0.f));
    o1.y = pck(fmaxf(fmaf(acc[2], dc, bias[cb + 2]), 0.f), fmaxf(fmaf(acc[3], dc, bias[cb + 3]), 0.f));
    o1.z = pck(fmaxf(fmaf(acc[4], dc, bias[cb + 4]), 0.f), fmaxf(fmaf(acc[5], dc, bias[cb + 5]), 0.f));
    o1.w = pck(fmaxf(fmaf(acc[6], dc, bias[cb + 6]), 0.f), fmaxf(fmaf(acc[7], dc, bias[cb + 7]), 0.f));
    o2.x = pck(fmaxf(fmaf(acc[8], dc, bias[cb + 8]), 0.f), fmaxf(fmaf(acc[9], dc, bias[cb + 9]), 0.f));
    o2.y = pck(fmaxf(fmaf(acc[10], dc, bias[cb + 10]), 0.f), fmaxf(fmaf(acc[11], dc, bias[cb + 11]), 0.f));
    o2.z = pck(fmaxf(fmaf(acc[12], dc, bias[cb + 12]), 0.f), fmaxf(fmaf(acc[13], dc, bias[cb + 13]), 0.f));
    o2.w = pck(fmaxf(fmaf(acc[14], dc, bias[cb + 14]), 0.f), fmaxf(fmaf(acc[15], dc, bias[cb + 15]), 0.f));
    out[(size_t)c * 16 + cp * 2] = o1;
    out[(size_t)c * 16 + cp * 2 + 1] = o2;
  }
}

// ---------------- nv GEMM + fused w5b GEMM (XOR-swizzled LDS restage) ----------------
// nv = [x1|x2|x3](K=384)@w2t + b2 (f32, output); pool partials;
// t = relu(nv)@w5bt (bf16 out) via swizzled LDS.

__global__ __launch_bounds__(256) void k_gnvt(
    const unsigned short* __restrict__ A1, const unsigned short* __restrict__ A2,
    const unsigned short* __restrict__ A3, const unsigned short* __restrict__ Bt,
    const unsigned short* __restrict__ W5bt, const float* __restrict__ b2,
    const int* __restrict__ sel, float* __restrict__ nv,
    unsigned short* __restrict__ tb, float* __restrict__ part, int n) {
  __shared__ float spart[HID];
  __shared__ unsigned char smb[64 * 256];  // 64 rows x 128 bf16, XOR-swizzled
  int tid = threadIdx.x, lane = tid & 63, wave = tid >> 6;
  if (tid < HID) spart[tid] = 0.f;
  int lm = lane & 15, lk = lane >> 4;
  int lrow0 = (wave >> 1) * 32;
  int row0 = blockIdx.x * 64 + lrow0;
  int col0 = (wave & 1) * 64;
  int ra = min(row0 + lm, n - 1), rb = min(row0 + 16 + lm, n - 1);
  f32x4 acc[2][4] = {};
  const unsigned short* As[3] = {A1, A2, A3};
#pragma unroll
  for (int kb = 0; kb < 3; ++kb) {
    const unsigned short* A = As[kb];
#pragma unroll
    for (int ks = 0; ks < 4; ++ks) {
      bf16x8 a0 = *reinterpret_cast<const bf16x8*>(A + (size_t)ra * HID + ks * 32 + lk * 8);
      bf16x8 a1 = *reinterpret_cast<const bf16x8*>(A + (size_t)rb * HID + ks * 32 + lk * 8);
#pragma unroll
      for (int ct = 0; ct < 4; ++ct) {
        bf16x8 bb = *reinterpret_cast<const bf16x8*>(
            Bt + (size_t)(col0 + ct * 16 + lm) * 384 + kb * 128 + ks * 32 + lk * 8);
        acc[0][ct] = __builtin_amdgcn_mfma_f32_16x16x32_bf16(a0, bb, acc[0][ct], 0, 0, 0);
        acc[1][ct] = __builtin_amdgcn_mfma_f32_16x16x32_bf16(a1, bb, acc[1][ct], 0, 0, 0);
      }
    }
  }
  float psum[4] = {0.f, 0.f, 0.f, 0.f};
#pragma unroll
  for (int rt = 0; rt < 2; ++rt)
#pragma unroll
    for (int r = 0; r < 4; ++r) {
      int row = row0 + rt * 16 + lk * 4 + r;
      int lr = lrow0 + rt * 16 + lk * 4 + r;
      int sw = (lr & 7) << 4;
      if (row < n) {
        float m = (sel[row] == 0) ? 1.f : 0.f;
#pragma unroll
        for (int ct = 0; ct < 4; ++ct) {
          int col = col0 + ct * 16 + lm;
          float v = acc[rt][ct][r] + b2[col];
          nv[(size_t)row * HID + col] = v;
          psum[ct] = fmaf(m, v, psum[ct]);
          *reinterpret_cast<unsigned short*>(smb + lr * 256 + ((col * 2) ^ sw)) =
              f2bf(fmaxf(v, 0.f));
        }
      } else {
#pragma unroll
        for (int ct = 0; ct < 4; ++ct) {
          int col = col0 + ct * 16 + lm;
          *reinterpret_cast<unsigned short*>(smb + lr * 256 + ((col * 2) ^ sw)) =
              f2bf(fmaxf(acc[rt][ct][r] + b2[col], 0.f));
        }
      }
    }
#pragma unroll
  for (int ct = 0; ct < 4; ++ct) {
    psum[ct] += __shfl_xor(psum[ct], 16);
    psum[ct] += __shfl_xor(psum[ct], 32);
  }
  __syncthreads();  // smb ready; spart init visible
  if (lk == 0) {
#pragma unroll
    for (int ct = 0; ct < 4; ++ct) atomicAdd(&spart[col0 + ct * 16 + lm], psum[ct]);
  }
  // phase B: t = relu(nv) @ w5b  (A from swizzled LDS)
  f32x4 acc2[2][4] = {};
  int rowa = lrow0 + lm, rowb = lrow0 + 16 + lm;
  int swa = (rowa & 7) << 4, swb = (rowb & 7) << 4;
#pragma unroll
  for (int ks = 0; ks < 4; ++ks) {
    bf16x8 a0 = *reinterpret_cast<const bf16x8*>(smb + rowa * 256 + ((ks * 64 + lk * 16) ^ swa));
    bf16x8 a1 = *reinterpret_cast<const bf16x8*>(smb + rowb * 256 + ((ks * 64 + lk * 16) ^ swb));
#pragma unroll
    for (int ct = 0; ct < 4; ++ct) {
      bf16x8 bb = *reinterpret_cast<const bf16x8*>(
          W5bt + (size_t)(col0 + ct * 16 + lm) * HID + ks * 32 + lk * 8);
      acc2[0][ct] = __builtin_amdgcn_mfma_f32_16x16x32_bf16(a0, bb, acc2[0][ct], 0, 0, 0);
      acc2[1][ct] = __builtin_amdgcn_mfma_f32_16x16x32_bf16(a1, bb, acc2[1][ct], 0, 0, 0);
    }
  }
  __syncthreads();  // spart atomics complete
  if (tid < HID) part[(size_t)blockIdx.x * HID + tid] = spart[tid];
#pragma unroll
  for (int rt = 0; rt < 2; ++rt)
#pragma unroll
    for (int r = 0; r < 4; ++r) {
      int row = row0 + rt * 16 + lk * 4 + r;
      if (row < n) {
#pragma unroll
        for (int ct = 0; ct < 4; ++ct)
          tb[(size_t)row * HID + col0 + ct * 16 + lm] = f2bf(acc2[rt][ct][r]);
      }
    }
}

// ---------------- parallel pool-final + g + gb5 (1 block x 1024 thr) ----------------

__global__ __launch_bounds__(1024) void k_g(const float* __restrict__ part, int nblk,
                                            const float* __restrict__ w6, const float* __restrict__ b6,
                                            const float* __restrict__ w5, const float* __restrict__ b5,
                                            float* __restrict__ gb5) {
  __shared__ float red[8][HID];
  __shared__ float p0[HID], gl[HID];
  int t = threadIdx.x, j = t & 127, grp = t >> 7;
  float a0 = 0.f, a1 = 0.f, a2 = 0.f, a3 = 0.f;
  int r = grp;
  for (; r + 32 <= nblk; r += 32) {
    a0 += part[(size_t)(r)*HID + j];
    a1 += part[(size_t)(r + 8) * HID + j];
    a2 += part[(size_t)(r + 16) * HID + j];
    a3 += part[(size_t)(r + 24) * HID + j];
  }
  for (; r < nblk; r += 8) a0 += part[(size_t)r * HID + j];
  red[grp][j] = (a0 + a1) + (a2 + a3);
  __syncthreads();
  if (grp == 0)
    p0[j] = ((red[0][j] + red[1][j]) + (red[2][j] + red[3][j])) +
            ((red[4][j] + red[5][j]) + (red[6][j] + red[7][j]));
  __syncthreads();
  float acc = 0.f;
#pragma unroll
  for (int k = 0; k < 16; ++k) acc = fmaf(p0[grp * 16 + k], w6[(grp * 16 + k) * HID + j], acc);
  red[grp][j] = acc;
  __syncthreads();
  if (grp == 0) {
    float s = ((red[0][j] + red[1][j]) + (red[2][j] + red[3][j])) +
              ((red[4][j] + red[5][j]) + (red[6][j] + red[7][j])) + b6[j];
    gl[j] = fmaxf(s, 0.f);
  }
  __syncthreads();
  acc = 0.f;
#pragma unroll
  for (int k = 0; k < 16; ++k) acc = fmaf(gl[grp * 16 + k], w5[(grp * 16 + k) * HID + j], acc);
  red[grp][j] = acc;
  __syncthreads();
  if (grp == 0)
    gb5[j] = ((red[0][j] + red[1][j]) + (red[2][j] + red[3][j])) +
             ((red[4][j] + red[5][j]) + (red[6][j] + red[7][j])) + b5[j];
}

// ---------------- final: q = relu(t + gb5) . w8 + b8 (wave per node) ----------------

__global__ __launch_bounds__(256) void k_q(const unsigned* __restrict__ t,
                                           const float* __restrict__ gb5,
                                           const float* __restrict__ w8,
                                           const float* __restrict__ b8,
                                           float* __restrict__ q, int n) {
  int wave = threadIdx.x >> 6, lane = threadIdx.x & 63;
  int i = blockIdx.x * 4 + wave;
  if (i >= n) return;
  unsigned u = t[(size_t)i * 64 + lane];
  float h0 = fmaxf(bflo(u) + gb5[2 * lane], 0.f);
  float h1 = fmaxf(bfhi(u) + gb5[2 * lane + 1], 0.f);
  float s = h0 * w8[2 * lane] + h1 * w8[2 * lane + 1];
#pragma unroll
  for (int d = 32; d; d >>= 1) s += __shfl_down(s, d);
  if (lane == 0) q[i] = s + b8[0];
}

// ---------------- launch ----------------

extern "C" void kernel_launch(void* const* d_in, const int* in_sizes, int n_in,
                              void* d_out, int out_size, void* d_ws, size_t ws_size,
                              hipStream_t stream) {
  const float* x   = (const float*)d_in[0];
  const int*   ei  = (const int*)d_in[1];
  const int*   sel = (const int*)d_in[2];
  const float* w1  = (const float*)d_in[3];
  const float* b1  = (const float*)d_in[4];
  const float* wc1 = (const float*)d_in[5];
  const float* bc1 = (const float*)d_in[6];
  const float* wc2 = (const float*)d_in[7];
  const float* bc2 = (const float*)d_in[8];
  const float* w2  = (const float*)d_in[9];
  const float* b2  = (const float*)d_in[10];
  const float* w5  = (const float*)d_in[11];
  const float* b5  = (const float*)d_in[12];
  const float* w6  = (const float*)d_in[13];
  const float* b6  = (const float*)d_in[14];
  const float* w8  = (const float*)d_in[15];
  const float* b8  = (const float*)d_in[16];

  int n = in_sizes[0] / 3;
  int e = in_sizes[1] / 2;
  const int* erow = ei;
  const int* ecol = ei + e;

  float* q  = (float*)d_out;
  float* nv = q + n;

  int g64 = (n + 63) / 64;
  int lgrid = (n * 64 + 255) / 256;
  int nbkt  = (n + 255) >> 8;
  int bgrid = (e + EPB - 1) / EPB;

  unsigned short* x1b = (unsigned short*)d_ws;            // [n,128] bf16
  unsigned short* x2b = x1b + (size_t)n * HID;            // [n,128] bf16
  unsigned short* x3b = x2b + (size_t)n * HID;            // [n,128] bf16
  unsigned char*  hb  = (unsigned char*)(x3b + (size_t)n * HID);  // [n,128] fp8
  unsigned short* tb  = (unsigned short*)(hb + (size_t)n * HID);  // [n,128] bf16
  unsigned short* wc1t = tb + (size_t)n * HID;
  unsigned short* wc2t = wc1t + HID * HID;
  unsigned short* w5bt = wc2t + HID * HID;
  unsigned short* w2t  = w5bt + HID * HID;                // [128][384] bf16
  float* fw = (float*)(w2t + 384 * HID);
  float* dinv  = fw; fw += n;
  float* part  = fw; fw += (size_t)g64 * HID;
  float* gb5   = fw; fw += HID;
  int* iw = (int*)fw;
  int* gcnt = iw; iw += 256;
  int* offg = iw; iw += n;
  int* cnt  = iw; iw += n;
  unsigned* ebuf = (unsigned*)iw; iw += (size_t)nbkt * CAP;   // packed r | lc<<16
  int* csr = iw;                                              // nbkt*CAP ints

  // launch 1: zero the 256 bucket counters
  hipMemsetAsync(gcnt, 0, 256 * sizeof(int), stream);
  // launch 2: bucket sort | weight prep | lin1 (bf16)
  k_pre<<<bgrid + 384 + lgrid, 256, 0, stream>>>(x, w1, b1, wc1, wc2, w5 + HID * HID, w2,
                                                 wc1t, wc2t, w5bt, w2t, (unsigned*)x1b,
                                                 erow, ecol, gcnt, ebuf, e, bgrid, n);
  // launch 3: per-bucket CSR/deg/dinv || conv1 GEMM (hb = x1@wc1, fp8 out)
  k_csrconv<<<nbkt + g64, 256, 0, stream>>>(ebuf, gcnt, csr, offg, cnt, dinv,
                                            x1b, wc1t, hb, n, nbkt);
  // launch 4: agg1 (x2 = relu(...), bf16)
  k_agg<<<(n + 3) / 4, 256, 0, stream>>>((const uint4*)hb, dinv, offg, cnt, csr, bc1, (uint4*)x2b, n);
  // launch 5: conv2 GEMM (hb = x2@wc2, fp8)
  k_gconv<<<g64, 256, 0, stream>>>(x2b, wc2t, hb, n);
  // launch 6: agg2 (x3 = relu(...), bf16)
  k_agg<<<(n + 3) / 4, 256, 0, stream>>>((const uint4*)hb, dinv, offg, cnt, csr, bc2, (uint4*)x3b, n);
  // launch 7: nv = [x1|x2|x3]@w2 + b2 (f32 out + pool partials) ; t = relu(nv)@w5b (bf16)
  k_gnvt<<<g64, 256, 0, stream>>>(x1b, x2b, x3b, w2t, w5bt, b2, sel, nv, tb, part, n);
  // launch 8: pool0 -> g -> gb5
  k_g<<<1, 1024, 0, stream>>>(part, g64, w6, b6, w5, b5, gb5);
  // launch 9: q = relu(t + gb5) . w8 + b8
  k_q<<<(n + 3) / 4, 256, 0, stream>>>((const unsigned*)tb, gb5, w8, b8, q, n);
}